// Round 10
// baseline (18.859 us; speedup 1.0000x reference)
//
#include <hip/hip_runtime.h>

// Single-dispatch analytic build of the 4 Floquet TBC Hamiltonians
// (NX=64, NY=32), real-part float32 layout out[k][r][c], k in [0,4),
// r,c in [0,2048). Site s = y*64 + x.
//
// Nonzero structure (verified cell-for-cell by the R6 scatter kernel, absmax 0):
//   H1 (k=0): d=r-c = +-64, lower site (x+y) even -> -1 ; d=+-1984, x odd  -> -cos(ty)
//   H3 (k=2): d=+-64, lower site (x+y) odd  -> -1 ; d=+-1984, x even -> -cos(ty)
//   H2 (k=1): d=+-1, lower x!=63, (x+y) odd  -> -1 ; d=+-63,  low%128==0 -> -cos(tx)
//   H4 (k=3): d=+-1, lower x!=63, (x+y) even -> -1 ; d=+-127, low%128==0 -> -cos(tx)
//
// R9 lesson: nontemporal stores cost ~2 us on this write-once stream (the
// rocclr fill hits 6.4 TB/s with plain stores) -> plain stores. Shape: 8
// cells (32 B) per thread, two dwordx4 stores, one pass (no grid-stride).

typedef float f32x4 __attribute__((ext_vector_type(4)));

__device__ inline float cellval(int k, int r, int c,
                                const float* __restrict__ tx,
                                const float* __restrict__ ty) {
    int d = r - c;
    int lo = (d > 0) ? c : r;              // lower-index site of the pair
    int x = lo & 63, y = lo >> 6;

    if ((k & 1) == 0) {                    // H1 / H3 : vertical bonds
        int want = (k == 0) ? 0 : 1;
        if (d == 64 || d == -64)
            return (((x + y) & 1) == want) ? -1.f : 0.f;
        if (d == 1984 || d == -1984) {     // y-wrap: low site in row y=0
            int xpar = (k == 0) ? 1 : 0;
            return ((x & 1) == xpar) ? -cosf(ty[0]) : 0.f;
        }
    } else {                               // H2 / H4 : horizontal bonds
        int want = (k == 1) ? 1 : 0;
        if (d == 1 || d == -1)
            return (x != 63 && ((x + y) & 1) == want) ? -1.f : 0.f;
        int wd = (k == 1) ? 63 : 127;
        if (d == wd || d == -wd)           // x-wrap: low site = 128*p
            return ((lo & 127) == 0) ? -cosf(tx[0]) : 0.f;
    }
    return 0.f;
}

__global__ __launch_bounds__(256) void build_kernel(
        f32x4* __restrict__ out, int n8,
        const float* __restrict__ theta_x,
        const float* __restrict__ theta_y) {
    int idx = blockIdx.x * blockDim.x + threadIdx.x;
    if (idx >= n8) return;

    int cell0 = idx << 3;                  // 8 consecutive cells, same row
    int k   = cell0 >> 22;                 // 2048*2048 = 2^22 cells per matrix
    int rem = cell0 & ((1 << 22) - 1);
    int r   = rem >> 11;
    int c0  = rem & 2047;
    int d0  = r - c0;                      // cell i has d = d0 - i, i in [0,8)

    // Band test: any of the 8 cells on a nonzero diagonal?
    // d0 in [D, D+7]  <=>  (unsigned)(d0 - D) < 8.
    bool slow;
    if ((k & 1) == 0) {
        slow = ((unsigned)(d0 - 64) < 8u)   | ((unsigned)(d0 + 64) < 8u) |
               ((unsigned)(d0 - 1984) < 8u) | ((unsigned)(d0 + 1984) < 8u);
    } else if (k == 1) {
        slow = ((unsigned)(d0 - 1) < 8u)    | ((unsigned)(d0 + 1) < 8u) |
               ((unsigned)(d0 - 63) < 8u)   | ((unsigned)(d0 + 63) < 8u);
    } else {
        slow = ((unsigned)(d0 - 1) < 8u)    | ((unsigned)(d0 + 1) < 8u) |
               ((unsigned)(d0 - 127) < 8u)  | ((unsigned)(d0 + 127) < 8u);
    }

    f32x4 v0 = (f32x4)(0.f);
    f32x4 v1 = (f32x4)(0.f);
    if (slow) {
        v0.x = cellval(k, r, c0,     theta_x, theta_y);
        v0.y = cellval(k, r, c0 + 1, theta_x, theta_y);
        v0.z = cellval(k, r, c0 + 2, theta_x, theta_y);
        v0.w = cellval(k, r, c0 + 3, theta_x, theta_y);
        v1.x = cellval(k, r, c0 + 4, theta_x, theta_y);
        v1.y = cellval(k, r, c0 + 5, theta_x, theta_y);
        v1.z = cellval(k, r, c0 + 6, theta_x, theta_y);
        v1.w = cellval(k, r, c0 + 7, theta_x, theta_y);
    }
    out[2 * idx]     = v0;
    out[2 * idx + 1] = v1;
}

extern "C" void kernel_launch(void* const* d_in, const int* in_sizes, int n_in,
                              void* d_out, int out_size, void* d_ws, size_t ws_size,
                              hipStream_t stream) {
    (void)in_sizes; (void)n_in; (void)d_ws; (void)ws_size;

    const float* theta_x = (const float*)d_in[0];
    const float* theta_y = (const float*)d_in[1];

    int n8 = out_size / 8;                 // 2,097,152 threads, 32 B each
    int blocks = (n8 + 255) / 256;         // 8192 workgroups x 256
    build_kernel<<<blocks, 256, 0, stream>>>((f32x4*)d_out, n8,
                                             theta_x, theta_y);
}

// Round 11
// 16.682 us; speedup vs baseline: 1.1305x; 1.1305x over previous
//
#include <hip/hip_runtime.h>

// Single-dispatch analytic build of the 4 Floquet TBC Hamiltonians
// (NX=64, NY=32), real-part float32 layout out[k][r][c], k in [0,4),
// r,c in [0,2048). Site s = y*64 + x.
//
// Nonzero structure (verified cell-for-cell by the R6 scatter kernel, absmax 0):
//   H1 (k=0): d=r-c = +-64, lower site (x+y) even -> -1 ; d=+-1984, x odd  -> -cos(ty)
//   H3 (k=2): d=+-64, lower site (x+y) odd  -> -1 ; d=+-1984, x even -> -cos(ty)
//   H2 (k=1): d=+-1, lower x!=63, (x+y) odd  -> -1 ; d=+-63,  low%128==0 -> -cos(tx)
//   H4 (k=3): d=+-1, lower x!=63, (x+y) even -> -1 ; d=+-127, low%128==0 -> -cos(tx)
//
// Tuning history: this exact shape (4 contiguous cells = 16 B per thread, one
// plain dwordx4 store, single pass) measured 16.5 us — within ~3% of the
// 64 MB store roofline (~10.5 us) + fixed graph overhead (~5.5 us).
// Nontemporal stores: +1.9 us (R9). 8 cells/thread (32 B, gapped wave
// pattern): +2.4 us (R10). Both reverted.

__device__ inline float cellval(int k, int r, int c,
                                const float* __restrict__ tx,
                                const float* __restrict__ ty) {
    int d = r - c;
    int lo = (d > 0) ? c : r;              // lower-index site of the pair
    int x = lo & 63, y = lo >> 6;

    if ((k & 1) == 0) {                    // H1 / H3 : vertical bonds
        int want = (k == 0) ? 0 : 1;
        if (d == 64 || d == -64)
            return (((x + y) & 1) == want) ? -1.f : 0.f;
        if (d == 1984 || d == -1984) {     // y-wrap: low site in row y=0
            int xpar = (k == 0) ? 1 : 0;
            return ((x & 1) == xpar) ? -cosf(ty[0]) : 0.f;
        }
    } else {                               // H2 / H4 : horizontal bonds
        int want = (k == 1) ? 1 : 0;
        if (d == 1 || d == -1)
            return (x != 63 && ((x + y) & 1) == want) ? -1.f : 0.f;
        int wd = (k == 1) ? 63 : 127;
        if (d == wd || d == -wd)           // x-wrap: low site = 128*p
            return ((lo & 127) == 0) ? -cosf(tx[0]) : 0.f;
    }
    return 0.f;
}

__global__ void build_kernel(float4* __restrict__ out, int n4,
                             const float* __restrict__ theta_x,
                             const float* __restrict__ theta_y) {
    int idx = blockIdx.x * blockDim.x + threadIdx.x;
    if (idx >= n4) return;

    int cell0 = idx << 2;                  // 4 consecutive cells, same row
    int k   = cell0 >> 22;                 // 2048*2048 = 2^22 cells per matrix
    int rem = cell0 & ((1 << 22) - 1);
    int r   = rem >> 11;
    int c0  = rem & 2047;
    int d0  = r - c0;                      // cell i has d = d0 - i, i in [0,4)

    // Band test: any of the 4 cells on a nonzero diagonal?
    // d0 in [D, D+3]  <=>  (unsigned)(d0 - D) < 4.
    bool slow;
    if ((k & 1) == 0) {
        slow = ((unsigned)(d0 - 64) < 4u)   | ((unsigned)(d0 + 64) < 4u) |
               ((unsigned)(d0 - 1984) < 4u) | ((unsigned)(d0 + 1984) < 4u);
    } else if (k == 1) {
        slow = ((unsigned)(d0 - 1) < 4u)    | ((unsigned)(d0 + 1) < 4u) |
               ((unsigned)(d0 - 63) < 4u)   | ((unsigned)(d0 + 63) < 4u);
    } else {
        slow = ((unsigned)(d0 - 1) < 4u)    | ((unsigned)(d0 + 1) < 4u) |
               ((unsigned)(d0 - 127) < 4u)  | ((unsigned)(d0 + 127) < 4u);
    }

    float4 v = make_float4(0.f, 0.f, 0.f, 0.f);
    if (slow) {
        v.x = cellval(k, r, c0,     theta_x, theta_y);
        v.y = cellval(k, r, c0 + 1, theta_x, theta_y);
        v.z = cellval(k, r, c0 + 2, theta_x, theta_y);
        v.w = cellval(k, r, c0 + 3, theta_x, theta_y);
    }
    out[idx] = v;
}

extern "C" void kernel_launch(void* const* d_in, const int* in_sizes, int n_in,
                              void* d_out, int out_size, void* d_ws, size_t ws_size,
                              hipStream_t stream) {
    (void)in_sizes; (void)n_in; (void)d_ws; (void)ws_size;

    const float* theta_x = (const float*)d_in[0];
    const float* theta_y = (const float*)d_in[1];

    int n4 = out_size / 4;                 // 4,194,304 float4 stores
    int blocks = (n4 + 255) / 256;         // 16384 workgroups x 256
    build_kernel<<<blocks, 256, 0, stream>>>((float4*)d_out, n4,
                                             theta_x, theta_y);
}